// Round 1
// baseline (995.224 us; speedup 1.0000x reference)
//
#include <hip/hip_runtime.h>

typedef __attribute__((ext_vector_type(4))) float f32x4;
typedef __attribute__((ext_vector_type(8))) __bf16 bf16x8;
typedef __attribute__((ext_vector_type(8))) unsigned short u16x8;
typedef __attribute__((ext_vector_type(4))) unsigned short u16x4;

#define MFMA16(a, b, c) \
  __builtin_amdgcn_mfma_f32_16x16x32_bf16(__builtin_bit_cast(bf16x8, (a)), \
                                          __builtin_bit_cast(bf16x8, (b)), (c), 0, 0, 0)

__device__ __forceinline__ unsigned short f2bf(float f) {
  unsigned int u = __builtin_bit_cast(unsigned int, f);
  u += 0x7FFFu + ((u >> 16) & 1u);   // RNE; inputs are finite
  return (unsigned short)(u >> 16);
}

// ---------------------------------------------------------------------------
// Kernel 1: transpose + fp32->bf16 convert the four weight matrices.
// Wt[z][n][k] = W_z[k][n], z in {Wq, Wk, Wv, Wo}. 1024x1024 each.
// grid (32, 32, 4), block (32, 8)
// ---------------------------------------------------------------------------
__global__ __launch_bounds__(256) void wtrans(
    const float* __restrict__ Wq, const float* __restrict__ Wk,
    const float* __restrict__ Wv, const float* __restrict__ Wo,
    unsigned short* __restrict__ Wt)
{
  __shared__ unsigned short tile[32][33];
  const int z = blockIdx.z;
  const float* W = (z == 0) ? Wq : (z == 1) ? Wk : (z == 2) ? Wv : Wo;
  unsigned short* T = Wt + (size_t)z * 1024 * 1024;
  const int tx = threadIdx.x, ty = threadIdx.y;
  const int x = blockIdx.x * 32 + tx;
  const int y0 = blockIdx.y * 32;
#pragma unroll
  for (int i = 0; i < 4; ++i)
    tile[ty + i * 8][tx] = f2bf(W[(size_t)(y0 + ty + i * 8) * 1024 + x]);
  __syncthreads();
#pragma unroll
  for (int i = 0; i < 4; ++i)
    T[(size_t)(blockIdx.x * 32 + ty + i * 8) * 1024 + y0 + tx] = tile[tx][ty + i * 8];
}

// ---------------------------------------------------------------------------
// Kernel 2: QKV projection GEMM. C[16384,1024] = X(fp32) @ W_z, stored bf16
// into Q/K/V with [B,H,S,DK] layout. 128x128 tile, BK=32, 4 waves, each wave
// a 64x64 quadrant via 4x4 MFMA 16x16x32 fragments.
// grid (8, 128, 3), block 256
// ---------------------------------------------------------------------------
__global__ __launch_bounds__(256) void qkv_gemm(
    const float* __restrict__ X, const unsigned short* __restrict__ Wt,
    unsigned short* __restrict__ Qo, unsigned short* __restrict__ Ko,
    unsigned short* __restrict__ Vo)
{
  const int bn = blockIdx.x * 128;
  const int bm = blockIdx.y * 128;
  const int z = blockIdx.z;
  const unsigned short* Wz = Wt + (size_t)z * 1024 * 1024;
  unsigned short* Out = (z == 0) ? Qo : (z == 1) ? Ko : Vo;

  const int tid = threadIdx.x;
  const int w = tid >> 6, l = tid & 63, l15 = l & 15, lg = l >> 4;
  const int wr = w >> 1, wc = w & 1;

  __shared__ alignas(16) unsigned short sA[128][32];
  __shared__ alignas(16) unsigned short sB[128][32];

  f32x4 acc[4][4];
  const f32x4 zero = {0.f, 0.f, 0.f, 0.f};
#pragma unroll
  for (int i = 0; i < 4; ++i)
#pragma unroll
    for (int j = 0; j < 4; ++j) acc[i][j] = zero;

  for (int k0 = 0; k0 < 1024; k0 += 32) {
    __syncthreads();
    // stage A (fp32 -> bf16): 128 rows x 32 k
#pragma unroll
    for (int p = 0; p < 2; ++p) {
      int id = p * 256 + tid;
      int row = id >> 2, c = id & 3;
      const float* src = X + (size_t)(bm + row) * 1024 + k0 + c * 8;
      f32x4 f0 = *(const f32x4*)(src);
      f32x4 f1 = *(const f32x4*)(src + 4);
      u16x8 v;
      v[0] = f2bf(f0[0]); v[1] = f2bf(f0[1]); v[2] = f2bf(f0[2]); v[3] = f2bf(f0[3]);
      v[4] = f2bf(f1[0]); v[5] = f2bf(f1[1]); v[6] = f2bf(f1[2]); v[7] = f2bf(f1[3]);
      *(u16x8*)&sA[row][c * 8] = v;
    }
    // stage B (already bf16, pre-transposed): 128 cols x 32 k
#pragma unroll
    for (int p = 0; p < 2; ++p) {
      int id = p * 256 + tid;
      int row = id >> 2, c = id & 3;
      *(u16x8*)&sB[row][c * 8] =
          *(const u16x8*)(Wz + (size_t)(bn + row) * 1024 + k0 + c * 8);
    }
    __syncthreads();

    u16x8 af[4], bf[4];
#pragma unroll
    for (int m = 0; m < 4; ++m)
      af[m] = *(const u16x8*)&sA[wr * 64 + m * 16 + l15][lg * 8];
#pragma unroll
    for (int n = 0; n < 4; ++n)
      bf[n] = *(const u16x8*)&sB[wc * 64 + n * 16 + l15][lg * 8];
#pragma unroll
    for (int m = 0; m < 4; ++m)
#pragma unroll
      for (int n = 0; n < 4; ++n)
        acc[m][n] = MFMA16(af[m], bf[n], acc[m][n]);
  }

  // store: C row (b*1024+s), col (h*64+dk) -> Out[b][h][s][dk] bf16
#pragma unroll
  for (int m = 0; m < 4; ++m) {
    int grow_b = bm + wr * 64 + m * 16 + lg * 4;
#pragma unroll
    for (int n = 0; n < 4; ++n) {
      int gcol = bn + wc * 64 + n * 16 + l15;
      int hh = gcol >> 6, dk = gcol & 63;
#pragma unroll
      for (int t = 0; t < 4; ++t) {
        int grow = grow_b + t;
        int bb = grow >> 10, s = grow & 1023;
        Out[(((size_t)(bb * 16 + hh)) * 1024 + s) * 64 + dk] = f2bf(acc[m][n][t]);
      }
    }
  }
}

// ---------------------------------------------------------------------------
// Kernel 3: fused attention. One block per (b, h, 64 q-rows); 4 waves, each
// owns 16 q-rows (Q in registers). Flash-style online softmax over 16 K/V
// tiles of 64 kpos. LDS rows are 128B -> XOR-chunk swizzle (^ (row&7)) to
// keep ds_read_b128 conflict-free.
// grid (16, 16, 16) = (qtile, h, b), block 256
// ---------------------------------------------------------------------------
__global__ __launch_bounds__(256) void attn(
    const unsigned short* __restrict__ Q, const unsigned short* __restrict__ Kb,
    const unsigned short* __restrict__ Vb, const float* __restrict__ LL,
    const float* __restrict__ btr, unsigned short* __restrict__ O)
{
  const int q0 = blockIdx.x * 64;
  const int h = blockIdx.y, b = blockIdx.z;
  const int tid = threadIdx.x;
  const int w = tid >> 6, l = tid & 63, l15 = l & 15, lg = l >> 4;

  __shared__ alignas(16) unsigned short sK[64][64];
  __shared__ alignas(16) unsigned short sVt[64][64];
  __shared__ alignas(16) unsigned short sP[4][16][64];

  const float bt = btr[h];
  const size_t bh = (size_t)(b * 16 + h) * (1024 * 64);
  const unsigned short* Qb = Q + bh;
  const unsigned short* Kp = Kb + bh;
  const unsigned short* Vp = Vb + bh;

  // Q fragments (A-operand): row = l15, k-chunks per lane-group
  u16x8 qf[2];
  {
    const unsigned short* qp = Qb + (size_t)(q0 + w * 16 + l15) * 64 + lg * 8;
    qf[0] = *(const u16x8*)qp;
    qf[1] = *(const u16x8*)(qp + 32);
  }

  float mrow[4], lrow[4];
  f32x4 o[4];
  const f32x4 zero = {0.f, 0.f, 0.f, 0.f};
#pragma unroll
  for (int t = 0; t < 4; ++t) { mrow[t] = -1e30f; lrow[t] = 0.f; }
#pragma unroll
  for (int dn = 0; dn < 4; ++dn) o[dn] = zero;

  const int qrow_base = q0 + w * 16 + lg * 4;

  for (int kt = 0; kt < 16; ++kt) {
    __syncthreads();
    // stage K tile [kp][d], swizzled chunks
#pragma unroll
    for (int p = 0; p < 2; ++p) {
      int id = p * 256 + tid;
      int kp = id >> 3, cc = id & 7;
      u16x8 v = *(const u16x8*)(Kp + (size_t)(kt * 64 + kp) * 64 + cc * 8);
      *(u16x8*)&sK[kp][(cc ^ (kp & 7)) * 8] = v;
    }
    // stage V transposed [d][kp], swizzled
#pragma unroll
    for (int p = 0; p < 4; ++p) {
      int id = p * 256 + tid;
      int vp = id >> 4, c4 = (id & 15) * 4;
      u16x4 v = *(const u16x4*)(Vp + (size_t)(kt * 64 + vp) * 64 + c4);
#pragma unroll
      for (int i = 0; i < 4; ++i) {
        int dd = c4 + i;
        int ch = (vp >> 3) ^ (dd & 7);
        sVt[dd][ch * 8 + (vp & 7)] = v[i];
      }
    }
    __syncthreads();

    // scores: S = Q @ K^T  (16 q-rows x 64 kpos per wave)
    f32x4 s[4];
#pragma unroll
    for (int jn = 0; jn < 4; ++jn) s[jn] = zero;
#pragma unroll
    for (int dc = 0; dc < 2; ++dc) {
#pragma unroll
      for (int jn = 0; jn < 4; ++jn) {
        int row = jn * 16 + l15;
        int ch = (dc * 4 + lg) ^ (row & 7);
        u16x8 kfr = *(const u16x8*)&sK[row][ch * 8];
        s[jn] = MFMA16(qf[dc], kfr, s[jn]);
      }
    }

    // scale + per-head-scaled lead-lag bias
#pragma unroll
    for (int t = 0; t < 4; ++t) {
      const float* llp = LL + (size_t)(qrow_base + t) * 1024 + kt * 64 + l15;
#pragma unroll
      for (int jn = 0; jn < 4; ++jn)
        s[jn][t] = s[jn][t] * 0.125f + bt * llp[jn * 16];
    }

    // online softmax (rows live across 16-lane groups; reduce via shfl_xor)
    float pb[4][4];
#pragma unroll
    for (int t = 0; t < 4; ++t) {
      float tm = fmaxf(fmaxf(s[0][t], s[1][t]), fmaxf(s[2][t], s[3][t]));
      tm = fmaxf(tm, __shfl_xor(tm, 1));
      tm = fmaxf(tm, __shfl_xor(tm, 2));
      tm = fmaxf(tm, __shfl_xor(tm, 4));
      tm = fmaxf(tm, __shfl_xor(tm, 8));
      float mn = fmaxf(mrow[t], tm);
      float sc = __expf(mrow[t] - mn);
      mrow[t] = mn;
      float rs = 0.f;
#pragma unroll
      for (int jn = 0; jn < 4; ++jn) {
        float p = __expf(s[jn][t] - mn);
        pb[jn][t] = p;
        rs += p;
      }
      rs += __shfl_xor(rs, 1);
      rs += __shfl_xor(rs, 2);
      rs += __shfl_xor(rs, 4);
      rs += __shfl_xor(rs, 8);
      lrow[t] = lrow[t] * sc + rs;
#pragma unroll
      for (int dn = 0; dn < 4; ++dn) o[dn][t] *= sc;
    }

    // P -> per-wave LDS (bf16), swizzled
#pragma unroll
    for (int t = 0; t < 4; ++t) {
      int row = lg * 4 + t;
#pragma unroll
      for (int jn = 0; jn < 4; ++jn) {
        int col = jn * 16 + l15;
        int ch = (col >> 3) ^ (row & 7);
        sP[w][row][ch * 8 + (col & 7)] = f2bf(pb[jn][t]);
      }
    }

    // PV: O += P @ V
#pragma unroll
    for (int kc = 0; kc < 2; ++kc) {
      int ch = (kc * 4 + lg) ^ (l15 & 7);
      u16x8 pa = *(const u16x8*)&sP[w][l15][ch * 8];
#pragma unroll
      for (int dn = 0; dn < 4; ++dn) {
        int vr = dn * 16 + l15;
        int vc = (kc * 4 + lg) ^ (vr & 7);
        u16x8 vfr = *(const u16x8*)&sVt[vr][vc * 8];
        o[dn] = MFMA16(pa, vfr, o[dn]);
      }
    }
  }

  // normalize + store O[b][s][h*64+d] bf16
#pragma unroll
  for (int t = 0; t < 4; ++t) {
    float inv = 1.f / lrow[t];
    size_t orow = ((size_t)b * 1024 + (qrow_base + t)) * 1024 + h * 64;
#pragma unroll
    for (int dn = 0; dn < 4; ++dn)
      O[orow + dn * 16 + l15] = f2bf(o[dn][t] * inv);
  }
}

// ---------------------------------------------------------------------------
// Kernel 4: output projection GEMM. out[16384,1024] fp32 = O(bf16) @ Wo.
// grid (8, 128), block 256
// ---------------------------------------------------------------------------
__global__ __launch_bounds__(256) void out_gemm(
    const unsigned short* __restrict__ A, const unsigned short* __restrict__ Bt,
    float* __restrict__ C)
{
  const int bn = blockIdx.x * 128;
  const int bm = blockIdx.y * 128;
  const int tid = threadIdx.x;
  const int w = tid >> 6, l = tid & 63, l15 = l & 15, lg = l >> 4;
  const int wr = w >> 1, wc = w & 1;

  __shared__ alignas(16) unsigned short sA[128][32];
  __shared__ alignas(16) unsigned short sB[128][32];

  f32x4 acc[4][4];
  const f32x4 zero = {0.f, 0.f, 0.f, 0.f};
#pragma unroll
  for (int i = 0; i < 4; ++i)
#pragma unroll
    for (int j = 0; j < 4; ++j) acc[i][j] = zero;

  for (int k0 = 0; k0 < 1024; k0 += 32) {
    __syncthreads();
#pragma unroll
    for (int p = 0; p < 2; ++p) {
      int id = p * 256 + tid;
      int row = id >> 2, c = id & 3;
      *(u16x8*)&sA[row][c * 8] =
          *(const u16x8*)(A + (size_t)(bm + row) * 1024 + k0 + c * 8);
      *(u16x8*)&sB[row][c * 8] =
          *(const u16x8*)(Bt + (size_t)(bn + row) * 1024 + k0 + c * 8);
    }
    __syncthreads();

    u16x8 af[4], bf[4];
#pragma unroll
    for (int m = 0; m < 4; ++m)
      af[m] = *(const u16x8*)&sA[wr * 64 + m * 16 + l15][lg * 8];
#pragma unroll
    for (int n = 0; n < 4; ++n)
      bf[n] = *(const u16x8*)&sB[wc * 64 + n * 16 + l15][lg * 8];
#pragma unroll
    for (int m = 0; m < 4; ++m)
#pragma unroll
      for (int n = 0; n < 4; ++n)
        acc[m][n] = MFMA16(af[m], bf[n], acc[m][n]);
  }

#pragma unroll
  for (int m = 0; m < 4; ++m) {
    int grow_b = bm + wr * 64 + m * 16 + lg * 4;
#pragma unroll
    for (int n = 0; n < 4; ++n) {
      int gcol = bn + wc * 64 + n * 16 + l15;
#pragma unroll
      for (int t = 0; t < 4; ++t)
        C[(size_t)(grow_b + t) * 1024 + gcol] = acc[m][n][t];
    }
  }
}

// ---------------------------------------------------------------------------
extern "C" void kernel_launch(void* const* d_in, const int* in_sizes, int n_in,
                              void* d_out, int out_size, void* d_ws, size_t ws_size,
                              hipStream_t stream) {
  const float* X  = (const float*)d_in[0];   // [16,1024,1024]
  const float* LL = (const float*)d_in[1];   // [1024,1024]
  const float* Wq = (const float*)d_in[2];
  const float* Wk = (const float*)d_in[3];
  const float* Wv = (const float*)d_in[4];
  const float* Wo = (const float*)d_in[5];
  const float* bt = (const float*)d_in[6];   // [16]
  float* out = (float*)d_out;

  unsigned short* ws = (unsigned short*)d_ws;
  const size_t QKV = (size_t)16 * 16 * 1024 * 64;   // 16M elems each
  unsigned short* Qb = ws;
  unsigned short* Kb = Qb + QKV;
  unsigned short* Vb = Kb + QKV;
  unsigned short* Ob = Vb + QKV;
  unsigned short* Wt = Ob + QKV;                    // 4 x 1M elems

  wtrans<<<dim3(32, 32, 4), dim3(32, 8), 0, stream>>>(Wq, Wk, Wv, Wo, Wt);
  qkv_gemm<<<dim3(8, 128, 3), 256, 0, stream>>>(X, Wt, Qb, Kb, Vb);
  attn<<<dim3(16, 16, 16), 256, 0, stream>>>(Qb, Kb, Vb, LL, bt, Ob);
  out_gemm<<<dim3(8, 128), 256, 0, stream>>>(Ob, Wt + 3 * 1024 * 1024, out);
}

// Round 4
// 599.502 us; speedup vs baseline: 1.6601x; 1.6601x over previous
//
#include <hip/hip_runtime.h>

typedef __attribute__((ext_vector_type(4))) float f32x4;
typedef __attribute__((ext_vector_type(8))) __bf16 bf16x8;
typedef __attribute__((ext_vector_type(8))) unsigned short u16x8;
typedef __attribute__((ext_vector_type(2))) unsigned int u32x2;

#define MFMA16(a, b, c) \
  __builtin_amdgcn_mfma_f32_16x16x32_bf16(__builtin_bit_cast(bf16x8, (a)), \
                                          __builtin_bit_cast(bf16x8, (b)), (c), 0, 0, 0)

__device__ __forceinline__ unsigned short f2bf(float f) {
  unsigned int u = __builtin_bit_cast(unsigned int, f);
  u += 0x7FFFu + ((u >> 16) & 1u);   // RNE; inputs are finite
  return (unsigned short)(u >> 16);
}

__device__ __forceinline__ unsigned int packbf(float lo, float hi) {
  return (unsigned int)f2bf(lo) | ((unsigned int)f2bf(hi) << 16);
}

// ---------------------------------------------------------------------------
// Kernel 1: transpose + fp32->bf16 convert the four weight matrices.
// Wt[z][n][k] = W_z[k][n]. grid (32,32,4), block (32,8)
// ---------------------------------------------------------------------------
__global__ __launch_bounds__(256) void wtrans(
    const float* __restrict__ Wq, const float* __restrict__ Wk,
    const float* __restrict__ Wv, const float* __restrict__ Wo,
    unsigned short* __restrict__ Wt)
{
  __shared__ unsigned short tile[32][33];
  const int z = blockIdx.z;
  const float* W = (z == 0) ? Wq : (z == 1) ? Wk : (z == 2) ? Wv : Wo;
  unsigned short* T = Wt + (size_t)z * 1024 * 1024;
  const int tx = threadIdx.x, ty = threadIdx.y;
  const int x = blockIdx.x * 32 + tx;
  const int y0 = blockIdx.y * 32;
#pragma unroll
  for (int i = 0; i < 4; ++i)
    tile[ty + i * 8][tx] = f2bf(W[(size_t)(y0 + ty + i * 8) * 1024 + x]);
  __syncthreads();
#pragma unroll
  for (int i = 0; i < 4; ++i)
    T[(size_t)(blockIdx.x * 32 + ty + i * 8) * 1024 + y0 + tx] = tile[tx][ty + i * 8];
}

// ---------------------------------------------------------------------------
// Kernel 2: QKV projection GEMM (proven). grid (8, 128, 3), block 256
// ---------------------------------------------------------------------------
__global__ __launch_bounds__(256) void qkv_gemm(
    const float* __restrict__ X, const unsigned short* __restrict__ Wt,
    unsigned short* __restrict__ Qo, unsigned short* __restrict__ Ko,
    unsigned short* __restrict__ Vo)
{
  const int bn = blockIdx.x * 128;
  const int bm = blockIdx.y * 128;
  const int z = blockIdx.z;
  const unsigned short* Wz = Wt + (size_t)z * 1024 * 1024;
  unsigned short* Out = (z == 0) ? Qo : (z == 1) ? Ko : Vo;

  const int tid = threadIdx.x;
  const int w = tid >> 6, l = tid & 63, l15 = l & 15, lg = l >> 4;
  const int wr = w >> 1, wc = w & 1;

  __shared__ alignas(16) unsigned short sA[128][32];
  __shared__ alignas(16) unsigned short sB[128][32];

  f32x4 acc[4][4];
  const f32x4 zero = {0.f, 0.f, 0.f, 0.f};
#pragma unroll
  for (int i = 0; i < 4; ++i)
#pragma unroll
    for (int j = 0; j < 4; ++j) acc[i][j] = zero;

  for (int k0 = 0; k0 < 1024; k0 += 32) {
    __syncthreads();
#pragma unroll
    for (int p = 0; p < 2; ++p) {
      int id = p * 256 + tid;
      int row = id >> 2, c = id & 3;
      const float* src = X + (size_t)(bm + row) * 1024 + k0 + c * 8;
      f32x4 f0 = *(const f32x4*)(src);
      f32x4 f1 = *(const f32x4*)(src + 4);
      u16x8 v;
      v[0] = f2bf(f0[0]); v[1] = f2bf(f0[1]); v[2] = f2bf(f0[2]); v[3] = f2bf(f0[3]);
      v[4] = f2bf(f1[0]); v[5] = f2bf(f1[1]); v[6] = f2bf(f1[2]); v[7] = f2bf(f1[3]);
      *(u16x8*)&sA[row][c * 8] = v;
    }
#pragma unroll
    for (int p = 0; p < 2; ++p) {
      int id = p * 256 + tid;
      int row = id >> 2, c = id & 3;
      *(u16x8*)&sB[row][c * 8] =
          *(const u16x8*)(Wz + (size_t)(bn + row) * 1024 + k0 + c * 8);
    }
    __syncthreads();

    u16x8 af[4], bf[4];
#pragma unroll
    for (int m = 0; m < 4; ++m)
      af[m] = *(const u16x8*)&sA[wr * 64 + m * 16 + l15][lg * 8];
#pragma unroll
    for (int n = 0; n < 4; ++n)
      bf[n] = *(const u16x8*)&sB[wc * 64 + n * 16 + l15][lg * 8];
#pragma unroll
    for (int m = 0; m < 4; ++m)
#pragma unroll
      for (int n = 0; n < 4; ++n)
        acc[m][n] = MFMA16(af[m], bf[n], acc[m][n]);
  }

#pragma unroll
  for (int m = 0; m < 4; ++m) {
    int grow_b = bm + wr * 64 + m * 16 + lg * 4;
#pragma unroll
    for (int n = 0; n < 4; ++n) {
      int gcol = bn + wc * 64 + n * 16 + l15;
      int hh = gcol >> 6, dk = gcol & 63;
#pragma unroll
      for (int t = 0; t < 4; ++t) {
        int grow = grow_b + t;
        int bb = grow >> 10, s = grow & 1023;
        Out[(((size_t)(bb * 16 + hh)) * 1024 + s) * 64 + dk] = f2bf(acc[m][n][t]);
      }
    }
  }
}

// ---------------------------------------------------------------------------
// Kernel 2b: V -> V^T per (b,h): Vt[b][h][d][s] = V[b][h][s][d].
// grid (16, 256), block 256
// ---------------------------------------------------------------------------
__global__ __launch_bounds__(256) void vtrans(
    const unsigned short* __restrict__ V, unsigned short* __restrict__ Vt)
{
  __shared__ unsigned short tile[64 * 64];
  const int s0 = blockIdx.x * 64;
  const size_t bh = (size_t)blockIdx.y * (64 * 1024);
  const int tid = threadIdx.x;

#pragma unroll
  for (int p = 0; p < 2; ++p) {
    int id = p * 256 + tid;
    int s = id >> 3, cc = id & 7;
    u16x8 v = *(const u16x8*)(V + bh + (size_t)(s0 + s) * 64 + cc * 8);
    *(u16x8*)&tile[s * 64 + ((cc ^ (s >> 3)) * 8)] = v;
  }
  __syncthreads();
#pragma unroll
  for (int p = 0; p < 2; ++p) {
    int id = p * 256 + tid;
    int d = id >> 3, sc = id & 7;
    u16x8 v;
#pragma unroll
    for (int i = 0; i < 8; ++i)
      v[i] = tile[(sc * 8 + i) * 64 + (((d >> 3) ^ sc) * 8) + (d & 7)];
    *(u16x8*)(Vt + bh + (size_t)d * 1024 + s0 + sc * 8) = v;
  }
}

// ---------------------------------------------------------------------------
// Kernel 3: fused attention, swapped-operand form (conservative build):
//   St = mfma(K, Q)  -> lane (l15,lg) holds scores for qrow=l15,
//                       kpos = jn*16 + lg*4 + t (lane-local q-row)
//   O^T = mfma(Vt, P) -> accumulator lane-local in qrow too.
// No cvt_pk asm (f2bf packs), no reg-prefetch (direct staging, proven
// double-barrier pattern), explicit 64-wide shuffles.
// grid (16, 16, 16) = (qtile, h, b), block 256
// ---------------------------------------------------------------------------
__global__ __launch_bounds__(256) void attn(
    const unsigned short* __restrict__ Q, const unsigned short* __restrict__ Kg,
    const unsigned short* __restrict__ Vtg, const float* __restrict__ LL,
    const float* __restrict__ btr, unsigned short* __restrict__ O)
{
  const int q0 = blockIdx.x * 64;
  const int h = blockIdx.y, b = blockIdx.z;
  const int tid = threadIdx.x;
  const int w = tid >> 6, l = tid & 63, l15 = l & 15, lg = l >> 4;

  __shared__ alignas(16) unsigned short sK[64 * 64];
  __shared__ alignas(16) unsigned short sVt[64 * 64];
  __shared__ alignas(16) unsigned short sP[4][16 * 64];

  const float bt = btr[h];
  const size_t bh = (size_t)(b * 16 + h) * (1024 * 64);
  const unsigned short* Qb = Q + bh;
  const unsigned short* Kp = Kg + bh;
  const unsigned short* Vp = Vtg + bh;

  // Q fragment (B-operand of swapped QK^T): col = qrow = l15, k = d
  u16x8 qf[2];
  {
    const unsigned short* qp = Qb + (size_t)(q0 + w * 16 + l15) * 64 + lg * 8;
    qf[0] = *(const u16x8*)qp;
    qf[1] = *(const u16x8*)(qp + 32);
  }
  const int qrow = q0 + w * 16 + l15;

  float mrow = -1e30f, lrow = 0.f;
  f32x4 o[4];
  const f32x4 zero = {0.f, 0.f, 0.f, 0.f};
#pragma unroll
  for (int dn = 0; dn < 4; ++dn) o[dn] = zero;

  const int srow0 = tid >> 3, scc = tid & 7;

  for (int kt = 0; kt < 16; ++kt) {
    __syncthreads();   // previous iteration's LDS reads done
    // stage K tile [kpos][d] and Vt tile [d][kpos], both chunk-swizzled
#pragma unroll
    for (int p = 0; p < 2; ++p) {
      int row = p * 32 + srow0;
      u16x8 vk = *(const u16x8*)(Kp + (size_t)(kt * 64 + row) * 64 + scc * 8);
      u16x8 vv = *(const u16x8*)(Vp + (size_t)row * 1024 + kt * 64 + scc * 8);
      *(u16x8*)&sK[row * 64 + ((scc ^ (row & 7)) * 8)] = vk;
      *(u16x8*)&sVt[row * 64 + ((scc ^ (row & 7)) * 8)] = vv;
    }
    __syncthreads();   // staging visible

    // bias loads early (L2/L3-resident; hide under MFMA)
    f32x4 llv[4];
#pragma unroll
    for (int jn = 0; jn < 4; ++jn)
      llv[jn] = *(const f32x4*)(LL + (size_t)qrow * 1024 + kt * 64 + jn * 16 + lg * 4);

    // scores: St = K @ Q^T (swapped) -> s[jn][t] for qrow=l15,
    // kpos = kt*64 + jn*16 + lg*4 + t
    f32x4 s[4];
#pragma unroll
    for (int jn = 0; jn < 4; ++jn) s[jn] = zero;
#pragma unroll
    for (int dc = 0; dc < 2; ++dc) {
#pragma unroll
      for (int jn = 0; jn < 4; ++jn) {
        int row = jn * 16 + l15;
        u16x8 kfr = *(const u16x8*)&sK[row * 64 + (((dc * 4 + lg) ^ (row & 7)) * 8)];
        s[jn] = MFMA16(kfr, qf[dc], s[jn]);
      }
    }

    // scale + per-head-scaled lead-lag bias
#pragma unroll
    for (int jn = 0; jn < 4; ++jn)
#pragma unroll
      for (int t = 0; t < 4; ++t)
        s[jn][t] = s[jn][t] * 0.125f + bt * llv[jn][t];

    // online softmax: q-row spans lanes (l15, lg=0..3) x 16 regs
    float tm = s[0][0];
#pragma unroll
    for (int jn = 0; jn < 4; ++jn)
#pragma unroll
      for (int t = 0; t < 4; ++t) tm = fmaxf(tm, s[jn][t]);
    tm = fmaxf(tm, __shfl_xor(tm, 16, 64));
    tm = fmaxf(tm, __shfl_xor(tm, 32, 64));
    float mn = fmaxf(mrow, tm);
    float sc = __expf(mrow - mn);
    mrow = mn;

    float rs = 0.f;
    unsigned int pk[4][2];
#pragma unroll
    for (int jn = 0; jn < 4; ++jn) {
      float p0 = __expf(s[jn][0] - mn);
      float p1 = __expf(s[jn][1] - mn);
      float p2 = __expf(s[jn][2] - mn);
      float p3 = __expf(s[jn][3] - mn);
      rs += (p0 + p1) + (p2 + p3);
      pk[jn][0] = packbf(p0, p1);
      pk[jn][1] = packbf(p2, p3);
    }
    rs += __shfl_xor(rs, 16, 64);
    rs += __shfl_xor(rs, 32, 64);
    lrow = lrow * sc + rs;
#pragma unroll
    for (int dn = 0; dn < 4; ++dn) o[dn] *= sc;

    // P -> per-wave LDS: kpos jn*16+lg*4+(0..3) at chunk-swizzled slot
#pragma unroll
    for (int jn = 0; jn < 4; ++jn) {
      int elem = l15 * 64 + (((jn * 2 + (lg >> 1)) ^ (l15 & 7)) * 8) + (lg & 1) * 4;
      u32x2 v2; v2[0] = pk[jn][0]; v2[1] = pk[jn][1];
      *(u32x2*)&sP[w][elem] = v2;
    }

    // PV: O^T += Vt @ P^T  (A = Vt frag, B = P frag)
#pragma unroll
    for (int kc = 0; kc < 2; ++kc) {
      u16x8 pb = *(const u16x8*)&sP[w][l15 * 64 + (((kc * 4 + lg) ^ (l15 & 7)) * 8)];
#pragma unroll
      for (int dn = 0; dn < 4; ++dn) {
        int vr = dn * 16 + l15;
        u16x8 vfr = *(const u16x8*)&sVt[vr * 64 + (((kc * 4 + lg) ^ (vr & 7)) * 8)];
        o[dn] = MFMA16(vfr, pb, o[dn]);
      }
    }
  }

  // normalize + store O[b][qrow][h*64 + d], d = dn*16 + lg*4 + t
  float inv = 1.f / lrow;
  unsigned short* Op = O + ((size_t)(b * 1024 + qrow)) * 1024 + h * 64;
#pragma unroll
  for (int dn = 0; dn < 4; ++dn) {
    u32x2 v2;
    v2[0] = packbf(o[dn][0] * inv, o[dn][1] * inv);
    v2[1] = packbf(o[dn][2] * inv, o[dn][3] * inv);
    *(u32x2*)(Op + dn * 16 + lg * 4) = v2;
  }
}

// ---------------------------------------------------------------------------
// Kernel 4: output projection GEMM (proven). grid (8, 128), block 256
// ---------------------------------------------------------------------------
__global__ __launch_bounds__(256) void out_gemm(
    const unsigned short* __restrict__ A, const unsigned short* __restrict__ Bt,
    float* __restrict__ C)
{
  const int bn = blockIdx.x * 128;
  const int bm = blockIdx.y * 128;
  const int tid = threadIdx.x;
  const int w = tid >> 6, l = tid & 63, l15 = l & 15, lg = l >> 4;
  const int wr = w >> 1, wc = w & 1;

  __shared__ alignas(16) unsigned short sA[128][32];
  __shared__ alignas(16) unsigned short sB[128][32];

  f32x4 acc[4][4];
  const f32x4 zero = {0.f, 0.f, 0.f, 0.f};
#pragma unroll
  for (int i = 0; i < 4; ++i)
#pragma unroll
    for (int j = 0; j < 4; ++j) acc[i][j] = zero;

  for (int k0 = 0; k0 < 1024; k0 += 32) {
    __syncthreads();
#pragma unroll
    for (int p = 0; p < 2; ++p) {
      int id = p * 256 + tid;
      int row = id >> 2, c = id & 3;
      *(u16x8*)&sA[row][c * 8] =
          *(const u16x8*)(A + (size_t)(bm + row) * 1024 + k0 + c * 8);
      *(u16x8*)&sB[row][c * 8] =
          *(const u16x8*)(Bt + (size_t)(bn + row) * 1024 + k0 + c * 8);
    }
    __syncthreads();

    u16x8 af[4], bf[4];
#pragma unroll
    for (int m = 0; m < 4; ++m)
      af[m] = *(const u16x8*)&sA[wr * 64 + m * 16 + l15][lg * 8];
#pragma unroll
    for (int n = 0; n < 4; ++n)
      bf[n] = *(const u16x8*)&sB[wc * 64 + n * 16 + l15][lg * 8];
#pragma unroll
    for (int m = 0; m < 4; ++m)
#pragma unroll
      for (int n = 0; n < 4; ++n)
        acc[m][n] = MFMA16(af[m], bf[n], acc[m][n]);
  }

#pragma unroll
  for (int m = 0; m < 4; ++m) {
    int grow_b = bm + wr * 64 + m * 16 + lg * 4;
#pragma unroll
    for (int n = 0; n < 4; ++n) {
      int gcol = bn + wc * 64 + n * 16 + l15;
#pragma unroll
      for (int t = 0; t < 4; ++t)
        C[(size_t)(grow_b + t) * 1024 + gcol] = acc[m][n][t];
    }
  }
}

// ---------------------------------------------------------------------------
extern "C" void kernel_launch(void* const* d_in, const int* in_sizes, int n_in,
                              void* d_out, int out_size, void* d_ws, size_t ws_size,
                              hipStream_t stream) {
  const float* X  = (const float*)d_in[0];   // [16,1024,1024]
  const float* LL = (const float*)d_in[1];   // [1024,1024]
  const float* Wq = (const float*)d_in[2];
  const float* Wk = (const float*)d_in[3];
  const float* Wv = (const float*)d_in[4];
  const float* Wo = (const float*)d_in[5];
  const float* bt = (const float*)d_in[6];   // [16]
  float* out = (float*)d_out;

  unsigned short* ws = (unsigned short*)d_ws;
  const size_t QKV = (size_t)16 * 16 * 1024 * 64;   // 16M elems each
  unsigned short* Qb = ws;
  unsigned short* Kb = Qb + QKV;
  unsigned short* Vb = Kb + QKV;       // dead after vtrans; reused as Ob
  unsigned short* Vt = Vb + QKV;
  unsigned short* Wt = Vt + QKV;       // 4 x 1M elems
  unsigned short* Ob = Vb;             // alias: attn output

  wtrans<<<dim3(32, 32, 4), dim3(32, 8), 0, stream>>>(Wq, Wk, Wv, Wo, Wt);
  qkv_gemm<<<dim3(8, 128, 3), 256, 0, stream>>>(X, Wt, Qb, Kb, Vb);
  vtrans<<<dim3(16, 256), 256, 0, stream>>>(Vb, Vt);
  attn<<<dim3(16, 16, 16), 256, 0, stream>>>(Qb, Kb, Vt, LL, bt, Ob);
  out_gemm<<<dim3(8, 128), 256, 0, stream>>>(Ob, Wt + 3 * 1024 * 1024, out);
}

// Round 5
// 506.533 us; speedup vs baseline: 1.9648x; 1.1835x over previous
//
#include <hip/hip_runtime.h>

typedef __attribute__((ext_vector_type(4))) float f32x4;
typedef __attribute__((ext_vector_type(8))) __bf16 bf16x8;
typedef __attribute__((ext_vector_type(8))) unsigned short u16x8;
typedef __attribute__((ext_vector_type(2))) unsigned int u32x2;

#define MFMA16(a, b, c) \
  __builtin_amdgcn_mfma_f32_16x16x32_bf16(__builtin_bit_cast(bf16x8, (a)), \
                                          __builtin_bit_cast(bf16x8, (b)), (c), 0, 0, 0)

__device__ __forceinline__ unsigned short f2bf(float f) {
  unsigned int u = __builtin_bit_cast(unsigned int, f);
  u += 0x7FFFu + ((u >> 16) & 1u);   // RNE; inputs are finite
  return (unsigned short)(u >> 16);
}

__device__ __forceinline__ unsigned int packbf(float lo, float hi) {
  return (unsigned int)f2bf(lo) | ((unsigned int)f2bf(hi) << 16);
}

// async global -> LDS, 16B per lane. Dest must be linear: HW writes
// wave-uniform-base + lane*16 (m104/m108). Per-lane ptr's first lane == base.
__device__ __forceinline__ void gload16(const void* g, void* l) {
  __builtin_amdgcn_global_load_lds(
      (const __attribute__((address_space(1))) void*)g,
      (__attribute__((address_space(3))) void*)l, 16, 0, 0);
}

// ---------------------------------------------------------------------------
// Kernel 0: X fp32 -> bf16. grid 8192, block 256.
// ---------------------------------------------------------------------------
__global__ __launch_bounds__(256) void xconv(
    const float* __restrict__ X, unsigned short* __restrict__ Xb)
{
  size_t i = ((size_t)blockIdx.x * 256 + threadIdx.x) * 8;
  f32x4 f0 = *(const f32x4*)(X + i);
  f32x4 f1 = *(const f32x4*)(X + i + 4);
  u16x8 v;
  v[0] = f2bf(f0[0]); v[1] = f2bf(f0[1]); v[2] = f2bf(f0[2]); v[3] = f2bf(f0[3]);
  v[4] = f2bf(f1[0]); v[5] = f2bf(f1[1]); v[6] = f2bf(f1[2]); v[7] = f2bf(f1[3]);
  *(u16x8*)(Xb + i) = v;
}

// ---------------------------------------------------------------------------
// Kernel 1: transpose + fp32->bf16 convert the four weight matrices.
// Wt[z][n][k] = W_z[k][n]. grid (32,32,4), block (32,8)
// ---------------------------------------------------------------------------
__global__ __launch_bounds__(256) void wtrans(
    const float* __restrict__ Wq, const float* __restrict__ Wk,
    const float* __restrict__ Wv, const float* __restrict__ Wo,
    unsigned short* __restrict__ Wt)
{
  __shared__ unsigned short tile[32][33];
  const int z = blockIdx.z;
  const float* W = (z == 0) ? Wq : (z == 1) ? Wk : (z == 2) ? Wv : Wo;
  unsigned short* T = Wt + (size_t)z * 1024 * 1024;
  const int tx = threadIdx.x, ty = threadIdx.y;
  const int x = blockIdx.x * 32 + tx;
  const int y0 = blockIdx.y * 32;
#pragma unroll
  for (int i = 0; i < 4; ++i)
    tile[ty + i * 8][tx] = f2bf(W[(size_t)(y0 + ty + i * 8) * 1024 + x]);
  __syncthreads();
#pragma unroll
  for (int i = 0; i < 4; ++i)
    T[(size_t)(blockIdx.x * 32 + ty + i * 8) * 1024 + y0 + tx] = tile[tx][ty + i * 8];
}

// ---------------------------------------------------------------------------
// Kernel 2: QKV projection GEMM, global_load_lds staging.
// C[16384,3072] = Xb(bf16) @ Wt; z folded into x so 24 consecutive blocks
// share one A panel (L2-hot). grid (24, 128), block 256.
// ---------------------------------------------------------------------------
__global__ __launch_bounds__(256) void qkv_gemm(
    const unsigned short* __restrict__ Xb, const unsigned short* __restrict__ Wt,
    unsigned short* __restrict__ Qo, unsigned short* __restrict__ Ko,
    unsigned short* __restrict__ Vo)
{
  const int bx = blockIdx.x;
  const int z = bx >> 3;
  const int bn = (bx & 7) * 128;
  const int bm = blockIdx.y * 128;
  const unsigned short* Wz = Wt + (size_t)z * 1024 * 1024;
  unsigned short* Out = (z == 0) ? Qo : (z == 1) ? Ko : Vo;

  const int tid = threadIdx.x;
  const int w = tid >> 6, l = tid & 63, l15 = l & 15, lg = l >> 4;
  const int wr = w >> 1, wc = w & 1;

  __shared__ alignas(16) unsigned short sA[128][32];
  __shared__ alignas(16) unsigned short sB[128][32];

  // staging: wave w covers rows [w*32, w*32+32); call p covers 16 rows.
  // lane l -> row +=(l>>2), col chunk (l&3)*8 elems; LDS linear to match.
  const int srow = w * 32 + (l >> 2);
  const int scol = (l & 3) * 8;
  const unsigned short* gA = Xb + (size_t)(bm + srow) * 1024 + scol;
  const unsigned short* gB = Wz + (size_t)(bn + srow) * 1024 + scol;
  unsigned short* lA = &sA[srow][scol];
  unsigned short* lB = &sB[srow][scol];

  f32x4 acc[4][4];
  const f32x4 zero = {0.f, 0.f, 0.f, 0.f};
#pragma unroll
  for (int i = 0; i < 4; ++i)
#pragma unroll
    for (int j = 0; j < 4; ++j) acc[i][j] = zero;

  for (int k0 = 0; k0 < 1024; k0 += 32) {
    __syncthreads();
#pragma unroll
    for (int p = 0; p < 2; ++p) {
      gload16(gA + (size_t)p * 16 * 1024 + k0, lA + p * 16 * 32);
      gload16(gB + (size_t)p * 16 * 1024 + k0, lB + p * 16 * 32);
    }
    __syncthreads();   // drains vmcnt -> staged data visible

    u16x8 af[4], bf[4];
#pragma unroll
    for (int m = 0; m < 4; ++m)
      af[m] = *(const u16x8*)&sA[wr * 64 + m * 16 + l15][lg * 8];
#pragma unroll
    for (int n = 0; n < 4; ++n)
      bf[n] = *(const u16x8*)&sB[wc * 64 + n * 16 + l15][lg * 8];
#pragma unroll
    for (int m = 0; m < 4; ++m)
#pragma unroll
      for (int n = 0; n < 4; ++n)
        acc[m][n] = MFMA16(af[m], bf[n], acc[m][n]);
  }

  // store: C row (b*1024+s), col (h*64+dk) -> Out[b][h][s][dk] bf16
#pragma unroll
  for (int m = 0; m < 4; ++m) {
    int grow_b = bm + wr * 64 + m * 16 + lg * 4;
#pragma unroll
    for (int n = 0; n < 4; ++n) {
      int gcol = bn + wc * 64 + n * 16 + l15;
      int hh = gcol >> 6, dk = gcol & 63;
#pragma unroll
      for (int t = 0; t < 4; ++t) {
        int grow = grow_b + t;
        int bb = grow >> 10, s = grow & 1023;
        Out[(((size_t)(bb * 16 + hh)) * 1024 + s) * 64 + dk] = f2bf(acc[m][n][t]);
      }
    }
  }
}

// ---------------------------------------------------------------------------
// Kernel 2b: V -> V^T per (b,h): Vt[b][h][d][s] = V[b][h][s][d].
// grid (16, 256), block 256
// ---------------------------------------------------------------------------
__global__ __launch_bounds__(256) void vtrans(
    const unsigned short* __restrict__ V, unsigned short* __restrict__ Vt)
{
  __shared__ unsigned short tile[64 * 64];
  const int s0 = blockIdx.x * 64;
  const size_t bh = (size_t)blockIdx.y * (64 * 1024);
  const int tid = threadIdx.x;

#pragma unroll
  for (int p = 0; p < 2; ++p) {
    int id = p * 256 + tid;
    int s = id >> 3, cc = id & 7;
    u16x8 v = *(const u16x8*)(V + bh + (size_t)(s0 + s) * 64 + cc * 8);
    *(u16x8*)&tile[s * 64 + ((cc ^ (s >> 3)) * 8)] = v;
  }
  __syncthreads();
#pragma unroll
  for (int p = 0; p < 2; ++p) {
    int id = p * 256 + tid;
    int d = id >> 3, sc = id & 7;
    u16x8 v;
#pragma unroll
    for (int i = 0; i < 8; ++i)
      v[i] = tile[(sc * 8 + i) * 64 + (((d >> 3) ^ sc) * 8) + (d & 7)];
    *(u16x8*)(Vt + bh + (size_t)d * 1024 + s0 + sc * 8) = v;
  }
}

// ---------------------------------------------------------------------------
// Kernel 3: fused attention, swapped-operand form (proven round-4 build).
// grid (16, 16, 16) = (qtile, h, b), block 256
// ---------------------------------------------------------------------------
__global__ __launch_bounds__(256) void attn(
    const unsigned short* __restrict__ Q, const unsigned short* __restrict__ Kg,
    const unsigned short* __restrict__ Vtg, const float* __restrict__ LL,
    const float* __restrict__ btr, unsigned short* __restrict__ O)
{
  const int q0 = blockIdx.x * 64;
  const int h = blockIdx.y, b = blockIdx.z;
  const int tid = threadIdx.x;
  const int w = tid >> 6, l = tid & 63, l15 = l & 15, lg = l >> 4;

  __shared__ alignas(16) unsigned short sK[64 * 64];
  __shared__ alignas(16) unsigned short sVt[64 * 64];
  __shared__ alignas(16) unsigned short sP[4][16 * 64];

  const float bt = btr[h];
  const size_t bh = (size_t)(b * 16 + h) * (1024 * 64);
  const unsigned short* Qb = Q + bh;
  const unsigned short* Kp = Kg + bh;
  const unsigned short* Vp = Vtg + bh;

  u16x8 qf[2];
  {
    const unsigned short* qp = Qb + (size_t)(q0 + w * 16 + l15) * 64 + lg * 8;
    qf[0] = *(const u16x8*)qp;
    qf[1] = *(const u16x8*)(qp + 32);
  }
  const int qrow = q0 + w * 16 + l15;

  float mrow = -1e30f, lrow = 0.f;
  f32x4 o[4];
  const f32x4 zero = {0.f, 0.f, 0.f, 0.f};
#pragma unroll
  for (int dn = 0; dn < 4; ++dn) o[dn] = zero;

  const int srow0 = tid >> 3, scc = tid & 7;

  for (int kt = 0; kt < 16; ++kt) {
    __syncthreads();
#pragma unroll
    for (int p = 0; p < 2; ++p) {
      int row = p * 32 + srow0;
      u16x8 vk = *(const u16x8*)(Kp + (size_t)(kt * 64 + row) * 64 + scc * 8);
      u16x8 vv = *(const u16x8*)(Vp + (size_t)row * 1024 + kt * 64 + scc * 8);
      *(u16x8*)&sK[row * 64 + ((scc ^ (row & 7)) * 8)] = vk;
      *(u16x8*)&sVt[row * 64 + ((scc ^ (row & 7)) * 8)] = vv;
    }
    __syncthreads();

    f32x4 llv[4];
#pragma unroll
    for (int jn = 0; jn < 4; ++jn)
      llv[jn] = *(const f32x4*)(LL + (size_t)qrow * 1024 + kt * 64 + jn * 16 + lg * 4);

    f32x4 s[4];
#pragma unroll
    for (int jn = 0; jn < 4; ++jn) s[jn] = zero;
#pragma unroll
    for (int dc = 0; dc < 2; ++dc) {
#pragma unroll
      for (int jn = 0; jn < 4; ++jn) {
        int row = jn * 16 + l15;
        u16x8 kfr = *(const u16x8*)&sK[row * 64 + (((dc * 4 + lg) ^ (row & 7)) * 8)];
        s[jn] = MFMA16(kfr, qf[dc], s[jn]);
      }
    }

#pragma unroll
    for (int jn = 0; jn < 4; ++jn)
#pragma unroll
      for (int t = 0; t < 4; ++t)
        s[jn][t] = s[jn][t] * 0.125f + bt * llv[jn][t];

    float tm = s[0][0];
#pragma unroll
    for (int jn = 0; jn < 4; ++jn)
#pragma unroll
      for (int t = 0; t < 4; ++t) tm = fmaxf(tm, s[jn][t]);
    tm = fmaxf(tm, __shfl_xor(tm, 16, 64));
    tm = fmaxf(tm, __shfl_xor(tm, 32, 64));
    float mn = fmaxf(mrow, tm);
    float sc = __expf(mrow - mn);
    mrow = mn;

    float rs = 0.f;
    unsigned int pk[4][2];
#pragma unroll
    for (int jn = 0; jn < 4; ++jn) {
      float p0 = __expf(s[jn][0] - mn);
      float p1 = __expf(s[jn][1] - mn);
      float p2 = __expf(s[jn][2] - mn);
      float p3 = __expf(s[jn][3] - mn);
      rs += (p0 + p1) + (p2 + p3);
      pk[jn][0] = packbf(p0, p1);
      pk[jn][1] = packbf(p2, p3);
    }
    rs += __shfl_xor(rs, 16, 64);
    rs += __shfl_xor(rs, 32, 64);
    lrow = lrow * sc + rs;
#pragma unroll
    for (int dn = 0; dn < 4; ++dn) o[dn] *= sc;

#pragma unroll
    for (int jn = 0; jn < 4; ++jn) {
      int elem = l15 * 64 + (((jn * 2 + (lg >> 1)) ^ (l15 & 7)) * 8) + (lg & 1) * 4;
      u32x2 v2; v2[0] = pk[jn][0]; v2[1] = pk[jn][1];
      *(u32x2*)&sP[w][elem] = v2;
    }

#pragma unroll
    for (int kc = 0; kc < 2; ++kc) {
      u16x8 pb = *(const u16x8*)&sP[w][l15 * 64 + (((kc * 4 + lg) ^ (l15 & 7)) * 8)];
#pragma unroll
      for (int dn = 0; dn < 4; ++dn) {
        int vr = dn * 16 + l15;
        u16x8 vfr = *(const u16x8*)&sVt[vr * 64 + (((kc * 4 + lg) ^ (vr & 7)) * 8)];
        o[dn] = MFMA16(vfr, pb, o[dn]);
      }
    }
  }

  float inv = 1.f / lrow;
  unsigned short* Op = O + ((size_t)(b * 1024 + qrow)) * 1024 + h * 64;
#pragma unroll
  for (int dn = 0; dn < 4; ++dn) {
    u32x2 v2;
    v2[0] = packbf(o[dn][0] * inv, o[dn][1] * inv);
    v2[1] = packbf(o[dn][2] * inv, o[dn][3] * inv);
    *(u32x2*)(Op + dn * 16 + lg * 4) = v2;
  }
}

// ---------------------------------------------------------------------------
// Kernel 4: output projection GEMM, global_load_lds staging.
// out[16384,1024] fp32 = Ob(bf16) @ WoT. grid (8, 128), block 256
// ---------------------------------------------------------------------------
__global__ __launch_bounds__(256) void out_gemm(
    const unsigned short* __restrict__ A, const unsigned short* __restrict__ Bt,
    float* __restrict__ C)
{
  const int bn = blockIdx.x * 128;
  const int bm = blockIdx.y * 128;
  const int tid = threadIdx.x;
  const int w = tid >> 6, l = tid & 63, l15 = l & 15, lg = l >> 4;
  const int wr = w >> 1, wc = w & 1;

  __shared__ alignas(16) unsigned short sA[128][32];
  __shared__ alignas(16) unsigned short sB[128][32];

  const int srow = w * 32 + (l >> 2);
  const int scol = (l & 3) * 8;
  const unsigned short* gA = A + (size_t)(bm + srow) * 1024 + scol;
  const unsigned short* gB = Bt + (size_t)(bn + srow) * 1024 + scol;
  unsigned short* lA = &sA[srow][scol];
  unsigned short* lB = &sB[srow][scol];

  f32x4 acc[4][4];
  const f32x4 zero = {0.f, 0.f, 0.f, 0.f};
#pragma unroll
  for (int i = 0; i < 4; ++i)
#pragma unroll
    for (int j = 0; j < 4; ++j) acc[i][j] = zero;

  for (int k0 = 0; k0 < 1024; k0 += 32) {
    __syncthreads();
#pragma unroll
    for (int p = 0; p < 2; ++p) {
      gload16(gA + (size_t)p * 16 * 1024 + k0, lA + p * 16 * 32);
      gload16(gB + (size_t)p * 16 * 1024 + k0, lB + p * 16 * 32);
    }
    __syncthreads();

    u16x8 af[4], bf[4];
#pragma unroll
    for (int m = 0; m < 4; ++m)
      af[m] = *(const u16x8*)&sA[wr * 64 + m * 16 + l15][lg * 8];
#pragma unroll
    for (int n = 0; n < 4; ++n)
      bf[n] = *(const u16x8*)&sB[wc * 64 + n * 16 + l15][lg * 8];
#pragma unroll
    for (int m = 0; m < 4; ++m)
#pragma unroll
      for (int n = 0; n < 4; ++n)
        acc[m][n] = MFMA16(af[m], bf[n], acc[m][n]);
  }

#pragma unroll
  for (int m = 0; m < 4; ++m) {
    int grow_b = bm + wr * 64 + m * 16 + lg * 4;
#pragma unroll
    for (int n = 0; n < 4; ++n) {
      int gcol = bn + wc * 64 + n * 16 + l15;
#pragma unroll
      for (int t = 0; t < 4; ++t)
        C[(size_t)(grow_b + t) * 1024 + gcol] = acc[m][n][t];
    }
  }
}

// ---------------------------------------------------------------------------
extern "C" void kernel_launch(void* const* d_in, const int* in_sizes, int n_in,
                              void* d_out, int out_size, void* d_ws, size_t ws_size,
                              hipStream_t stream) {
  const float* X  = (const float*)d_in[0];   // [16,1024,1024]
  const float* LL = (const float*)d_in[1];   // [1024,1024]
  const float* Wq = (const float*)d_in[2];
  const float* Wk = (const float*)d_in[3];
  const float* Wv = (const float*)d_in[4];
  const float* Wo = (const float*)d_in[5];
  const float* bt = (const float*)d_in[6];   // [16]
  float* out = (float*)d_out;

  unsigned short* ws = (unsigned short*)d_ws;
  const size_t QKV = (size_t)16 * 16 * 1024 * 64;   // 16M elems each
  unsigned short* Qb = ws;
  unsigned short* Kb = Qb + QKV;
  unsigned short* Vb = Kb + QKV;       // dead after vtrans; reused as Ob
  unsigned short* Vt = Vb + QKV;
  unsigned short* Wt = Vt + QKV;       // 4 x 1M elems
  unsigned short* Ob = Vb;             // alias: attn output
  unsigned short* Xbb = Vt;            // alias: Xb dead before vtrans writes Vt

  xconv<<<dim3(8192), 256, 0, stream>>>(X, Xbb);
  wtrans<<<dim3(32, 32, 4), dim3(32, 8), 0, stream>>>(Wq, Wk, Wv, Wo, Wt);
  qkv_gemm<<<dim3(24, 128), 256, 0, stream>>>(Xbb, Wt, Qb, Kb, Vb);
  vtrans<<<dim3(16, 256), 256, 0, stream>>>(Vb, Vt);
  attn<<<dim3(16, 16, 16), 256, 0, stream>>>(Qb, Kb, Vt, LL, bt, Ob);
  out_gemm<<<dim3(8, 128), 256, 0, stream>>>(Ob, Wt + 3 * 1024 * 1024, out);
}